// Round 15
// baseline (3179.803 us; speedup 1.0000x reference)
//
#include <hip/hip_runtime.h>

typedef __attribute__((ext_vector_type(8))) short short8;
typedef __attribute__((ext_vector_type(4))) float f32x4;
typedef unsigned short u16;
typedef unsigned int u32;
typedef unsigned long long u64;

// Shapes: B=16, T_ENC=256, T_DEC=64, N_MEL=80, ENC=512, ARNN=DRNN=1024,
// PRENET=256, ATTN_DIM=128, LOC_F=32, LOC_K=31
// attn LSTM K = 1792 (56 tiles of 32); dec K = 2560 (80 tiles)
// MFMA 16x16x32 bf16; C/D: col=lane&15, row=(lane>>4)*4+reg  [HW-verified]
//
// r15: gating population 128 -> 16. attn-LSTM on 16 blocks (256 gate rows
// each; per wave 2 row-tiles x full K -> NO cross-wave reduction), dec-LSTM
// on 16 separate blocks (off critical path, NT loads protect L2), phase-B on
// 16 blocks. Step gate = max over 16 producers (was 128) -> straggler tail
// shrinks ~ln(128)/ln(16). Direct 16-line flag polls, no aggregator hop.
// Coherence: writes agent-scope (LLC); reads plain cached on step-versioned
// virgin addresses (flag-gated; stale L1/L2 lines impossible; replay-safe).

// ---------------- workspace byte offsets ----------------
static constexpr size_t OFF_WFA   = 0;                 // 14,680,064
static constexpr size_t OFF_WFD   = 14680064;          // +20,971,520 = 35,651,584
static constexpr size_t OFF_PREF  = 35651584;          // +524,288
static constexpr size_t OFF_QWF   = 36175872;          // +262,144  qW A-frags
static constexpr size_t OFF_MWT   = 36438016;          // +262,144
static constexpr size_t OFF_BA    = 36700160;          // +16,384
static constexpr size_t OFF_BD    = 36716544;          // +16,384
static constexpr size_t OFF_PM    = 36732928;          // +2,097,152  pm[b][tt][d] f32
static constexpr size_t OFF_CTXF  = 38830080;          // +2,129,920  [t][b][d] f32
static constexpr size_t OFF_DHF   = 40960000;          // +4,259,840  [t][u][b] f32
static constexpr size_t OFF_AHFD  = 45219840;          // +2,129,920  65 x 32KB frag
static constexpr size_t OFF_CTXFD = 47349760;          // +1,064,960  65 x 16KB frag
static constexpr size_t OFF_DHFD  = 48414720;          // +2,129,920  65 x 32KB frag
static constexpr size_t OFF_BAR   = 50544640;          // Af@0 Df@1024 Bf@2048 (16x64B each)
static constexpr size_t OFF_END   = 50548736;

__device__ __forceinline__ float sigmf(float x) { return 1.f / (1.f + expf(-x)); }
__device__ __forceinline__ float tanh_fast(float x) {
  float e2 = __expf(2.f * x);
  return 1.f - 2.f / (e2 + 1.f);
}
__device__ __forceinline__ u16 f2bf(float f) {
  u32 u = __float_as_uint(f);
  return (u16)((u + 0x7FFFu + ((u >> 16) & 1u)) >> 16);
}
__device__ __forceinline__ float bf2f(u16 x) { return __uint_as_float(((u32)x) << 16); }

__device__ __forceinline__ short8 ld_frag(const void* p) {
  return *(const short8*)p;
}
// nontemporal (no cache allocation) - used only by dec blocks to keep L2 clean
__device__ __forceinline__ short8 ld_frag_nt(const void* p) {
  const u64* q = (const u64*)p;
  u64 lo = __builtin_nontemporal_load(q);
  u64 hi = __builtin_nontemporal_load(q + 1);
  union { u64 q2[2]; short8 s; } u;
  u.q2[0] = lo; u.q2[1] = hi;
  return u.s;
}

// agent-scope helpers (UC path)
__device__ __forceinline__ void st_u16_agent(u16* p, u16 v) {
  __hip_atomic_store(p, v, __ATOMIC_RELAXED, __HIP_MEMORY_SCOPE_AGENT);
}
__device__ __forceinline__ void st_f32_agent(float* p, float v) {
  __hip_atomic_store(p, v, __ATOMIC_RELAXED, __HIP_MEMORY_SCOPE_AGENT);
}
__device__ __forceinline__ void st_u64_agent(u64* p, u64 v) {
  __hip_atomic_store(p, v, __ATOMIC_RELAXED, __HIP_MEMORY_SCOPE_AGENT);
}
__device__ __forceinline__ u32 ld_u32_agent(const u32* p) {
  return __hip_atomic_load(p, __ATOMIC_RELAXED, __HIP_MEMORY_SCOPE_AGENT);
}
__device__ __forceinline__ void st_u32_agent(u32* p, u32 v) {
  __hip_atomic_store(p, v, __ATOMIC_RELAXED, __HIP_MEMORY_SCOPE_AGENT);
}

// 16-producer wait: first wave polls 16 strided lines, then block barrier
template <int SLP>
__device__ __forceinline__ void wait16(const u32* F, u32 target, int th) {
  if (th < 64) {
    const u32* pf = F + (th & 15) * 16;
    for (;;) {
      u32 v = ld_u32_agent(pf);
      if (__all(v >= target)) break;
      __builtin_amdgcn_s_sleep(SLP);
    }
  }
  __syncthreads();
}

// ---------------- prep: LSTM weights -> bf16 A-fragment layout ----------------
__global__ void k_wfrag(const float* __restrict__ Wih, const float* __restrict__ Whh,
                        char* __restrict__ dst, int NT, int Kih) {
  int idx = blockIdx.x * 256 + threadIdx.x;   // (tile*NT + s)*64 + l
  int l = idx & 63;
  int st = idx >> 6;
  int s = st % NT, tile = st / NT;
  int r = l & 15, kg = l >> 4;
  int j = (r >> 2) * 1024 + tile * 4 + (r & 3);
  int k0 = s * 32 + kg * 8;
  const float* src = (k0 < Kih) ? (Wih + (size_t)j * Kih + k0)
                                : (Whh + (size_t)j * 1024 + (k0 - Kih));
  short8 v;
#pragma unroll
  for (int e = 0; e < 8; ++e) v[e] = (short)f2bf(src[e]);
  *(short8*)(dst + (size_t)idx * 16) = v;
}

// ---------------- prep: qW -> bf16 A-fragments (8 d-tiles x 32 k-tiles) -------
__global__ void k_qwfrag(const float* __restrict__ qW, char* __restrict__ dst) {
  int idx = blockIdx.x * 256 + threadIdx.x;   // tile*64 + l, 16384 total
  int l = idx & 63, tile = idx >> 6;
  int dt = tile >> 5, kt = tile & 31;
  int j = dt * 16 + (l & 15);
  int k0 = kt * 32 + (l >> 4) * 8;
  short8 v;
#pragma unroll
  for (int e = 0; e < 8; ++e) v[e] = (short)f2bf(qW[j * 1024 + k0 + e]);
  *(short8*)(dst + (size_t)idx * 16) = v;
}

// ---------------- prep: memW^T, combined biases ----------------
__global__ void k_smallprep(const float* __restrict__ memW,
                            const float* __restrict__ abih, const float* __restrict__ abhh,
                            const float* __restrict__ dbih, const float* __restrict__ dbhh,
                            char* __restrict__ wsb) {
  int idx = blockIdx.x * 256 + threadIdx.x;
  if (idx < 65536) {
    int k = idx >> 7, d = idx & 127;
    ((float*)(wsb + OFF_MWT))[idx] = memW[d * 512 + k];
  } else if (idx < 69632) {
    int j = idx - 65536;
    ((float*)(wsb + OFF_BA))[j] = abih[j] + abhh[j];
  } else if (idx < 73728) {
    int j = idx - 69632;
    ((float*)(wsb + OFF_BD))[j] = dbih[j] + dbhh[j];
  }
}

// ---------------- prep: prenet -> bf16 B-fragment layout per step ----------------
__global__ void k_prenet(const float* __restrict__ dec_in,
                         const float* __restrict__ W1, const float* __restrict__ b1,
                         const float* __restrict__ W2, const float* __restrict__ b2,
                         char* __restrict__ wsb) {
  int s = blockIdx.x, b = blockIdx.y, th = threadIdx.x;
  __shared__ float frame[80];
  __shared__ float h1[256];
  if (th < 80) frame[th] = (s == 0) ? 0.f : dec_in[(b * 80 + th) * 64 + (s - 1)];
  __syncthreads();
  float a = b1[th];
  const float* w1r = W1 + th * 80;
  for (int m = 0; m < 80; ++m) a += w1r[m] * frame[m];
  h1[th] = fmaxf(a, 0.f);
  __syncthreads();
  float a2 = b2[th];
  const float* w2r = W2 + th * 256;
  for (int i = 0; i < 256; ++i) a2 += w2r[i] * h1[i];
  float pre = fmaxf(a2, 0.f);
  int k = th;
  ((u16*)(wsb + OFF_PREF))[(((size_t)s * 8 + (k >> 5)) * 64 + ((k >> 3) & 3) * 16 + b) * 8 + (k & 7)] = f2bf(pre);
}

// ---------------- prep: processed_memory pm[b][tt][d] ----------------
__global__ void k_pm(const float* __restrict__ memory, char* __restrict__ wsb) {
  int bk = blockIdx.x, th = threadIdx.x;
  int b = bk >> 4, t0 = (bk & 15) * 16;
  __shared__ float mrow[16 * 512];
  for (int i = 0; i < 8; ++i) {
    int fi4 = i * 256 + th;
    int tl = fi4 >> 7, k4 = (fi4 & 127) << 2;
    *(float4*)&mrow[tl * 512 + k4] =
        *(const float4*)&memory[((size_t)(b * 256 + t0 + tl)) * 512 + k4];
  }
  __syncthreads();
  int d = th & 127, tl0 = th >> 7;
  float acc[8] = {};
  const float* mWT = (const float*)(wsb + OFF_MWT);
  float* pmw = (float*)(wsb + OFF_PM);
  for (int k = 0; k < 512; ++k) {
    float w = mWT[k * 128 + d];
#pragma unroll
    for (int i = 0; i < 8; ++i) acc[i] += w * mrow[(tl0 + i * 2) * 512 + k];
  }
  for (int i = 0; i < 8; ++i)
    pmw[((size_t)(b * 256 + t0 + tl0 + i * 2)) * 128 + d] = acc[i];
}

struct KParams {
  const float* memory;
  const int* mlen;
  const float* convW;
  const float* ldW;
  const float* attnv;
  const float* projW;
  const float* projb;
  const float* gateW;
  const float* gateb;
  char* wsb;
  float* out;
};

// ---------------- main persistent kernel ----------------
// Roles: bk 0..15 phase-B(b); bk 16..31 attn-LSTM (16 rowtiles each);
//        bk 32..47 dec-LSTM (16 rowtiles each, NT loads); bk 48..255 idle.
__global__ void __launch_bounds__(512, 1) k_main(KParams p) {
  const int th = threadIdx.x;
  const int bk = blockIdx.x;
  char* wsb = p.wsb;
  const int l = th & 63, w = th >> 6;
  u32* Af = (u32*)(wsb + OFF_BAR);            // 16 strided
  u32* Df = (u32*)(wsb + OFF_BAR + 1024);     // 16 strided
  u32* Bf = (u32*)(wsb + OFF_BAR + 2048);     // 16 strided

  __shared__ float smC[4608];
  __shared__ float s2q[128], s2v[128];
  __shared__ u16 s_convF[8192];
  __shared__ u16 s_pack[512];
  __shared__ float s_e[256], s3wr[4];
  __shared__ float s1cw[1984];
  __shared__ float s_aw[256], s_awc[256];
  __shared__ float smW[4096];                 // 8 waves x 512 gate slab
  __shared__ u16 sp[1024];                    // 8 waves x 128 pack

  const float* pm = (const float*)(wsb + OFF_PM);

  if (bk < 16) {
    for (int i = th; i < 1984; i += 512) s1cw[i] = p.convW[i];
    for (int i = th; i < 4096; i += 512) ((u32*)s_convF)[i] = 0u;
    if (th < 128) s2v[th] = p.attnv[th];
    if (th < 256) { s_aw[th] = 0.f; s_awc[th] = 0.f; }
  }
  int lenB = 0;
  if (bk < 16) lenB = p.mlen[bk];

  short8 ldwB[8];
  if (bk < 16) {
    int kg = l >> 4, dcol = l & 15;
#pragma unroll
    for (int dt = 0; dt < 8; ++dt) {
      short8 v;
#pragma unroll
      for (int e = 0; e < 8; ++e)
        v[e] = (short)f2bf(p.ldW[(dt * 16 + dcol) * 32 + kg * 8 + e]);
      ldwB[dt] = v;
    }
  }
  __syncthreads();

  if (bk >= 16 && bk < 32) {
    // ================= attn-LSTM: block i owns row-tiles [i*16, i*16+16) ======
    const int i = bk - 16;
    const char* wfa = wsb + OFF_WFA;
    const int tI0 = i * 16 + w * 2;             // wave's 2 row-tiles
    // per-lane: 2 (unit,b) pairs; biases preloaded
    float bA[2][4], cA2[2] = {0.f, 0.f};
    {
      const float* ba = (const float*)(wsb + OFF_BA);
#pragma unroll
      for (int pq = 0; pq < 2; ++pq) {
        int idx = l * 2 + pq, lu = idx >> 4;
        int u = i * 64 + w * 8 + lu;
#pragma unroll
        for (int g = 0; g < 4; ++g) bA[pq][g] = ba[g * 1024 + u];
      }
    }
    f32x4 acc0, acc1;
    // early(t): PREF (8) + AHFD (32) K-tiles
    auto EARLY = [&](int t) {
      acc0 = f32x4{0.f, 0.f, 0.f, 0.f};
      acc1 = f32x4{0.f, 0.f, 0.f, 0.f};
      for (int e = 0; e < 40; ++e) {
        int s = (e < 8) ? e : (24 + (e - 8));
        const char* bsrc = (e < 8)
            ? wsb + OFF_PREF + (((size_t)t * 8 + s) * 64 + l) * 16
            : wsb + OFF_AHFD + (((size_t)t * 32 + (s - 24)) * 64 + l) * 16;
        short8 bv = ld_frag(bsrc);
        short8 a0 = *(const short8*)(wfa + (((size_t)tI0 * 56 + s) * 64 + l) * 16);
        short8 a1 = *(const short8*)(wfa + (((size_t)(tI0 + 1) * 56 + s) * 64 + l) * 16);
        acc0 = __builtin_amdgcn_mfma_f32_16x16x32_bf16(a0, bv, acc0, 0, 0, 0);
        acc1 = __builtin_amdgcn_mfma_f32_16x16x32_bf16(a1, bv, acc1, 0, 0, 0);
      }
    };
    EARLY(0);
    for (int t = 0; t < 64; ++t) {
      wait16<1>(Bf, (u32)t, th);                // ctx(t-1) ready
#pragma unroll
      for (int s = 8; s < 24; ++s) {            // late: CTXFD K-tiles
        short8 bv = ld_frag(wsb + OFF_CTXFD + (((size_t)t * 16 + (s - 8)) * 64 + l) * 16);
        short8 a0 = *(const short8*)(wfa + (((size_t)tI0 * 56 + s) * 64 + l) * 16);
        short8 a1 = *(const short8*)(wfa + (((size_t)(tI0 + 1) * 56 + s) * 64 + l) * 16);
        acc0 = __builtin_amdgcn_mfma_f32_16x16x32_bf16(a0, bv, acc0, 0, 0, 0);
        acc1 = __builtin_amdgcn_mfma_f32_16x16x32_bf16(a1, bv, acc1, 0, 0, 0);
      }
      {  // gates -> wave slab
        float* myW = smW + w * 512;
#pragma unroll
        for (int r4 = 0; r4 < 4; ++r4) {
          myW[((l >> 4) * 4 + r4) * 16 + (l & 15)] = acc0[r4];
          myW[256 + ((l >> 4) * 4 + r4) * 16 + (l & 15)] = acc1[r4];
        }
      }
      __syncthreads();
      {  // pointwise: 2 pairs per lane
        const float* myW = smW + w * 512;
        u16* myP = sp + w * 128;
#pragma unroll
        for (int pq = 0; pq < 2; ++pq) {
          int idx = l * 2 + pq, lu = idx >> 4, b = idx & 15;
          int rt = lu >> 2, uoff = lu & 3;
          float gi = myW[rt * 256 + (0 * 4 + uoff) * 16 + b] + bA[pq][0];
          float gf = myW[rt * 256 + (1 * 4 + uoff) * 16 + b] + bA[pq][1];
          float gg = myW[rt * 256 + (2 * 4 + uoff) * 16 + b] + bA[pq][2];
          float go = myW[rt * 256 + (3 * 4 + uoff) * 16 + b] + bA[pq][3];
          float c2 = sigmf(gf) * cA2[pq] + sigmf(gi) * tanhf(gg);
          float h2 = sigmf(go) * tanhf(c2);
          cA2[pq] = c2;
          myP[b * 8 + lu] = f2bf(h2);
        }
      }
      __syncthreads();
      if (l < 16) {  // publish wave slab: 16 lanes x 16B contiguous
        const u64* src = (const u64*)(sp + w * 128) + l * 2;
        int slab = i * 8 + w;
        u64* dst = (u64*)(wsb + OFF_AHFD + ((size_t)(t + 1) * 32 + (slab >> 2)) * 1024 +
                          ((size_t)((slab & 3) * 16 + l)) * 16);
        st_u64_agent(dst, src[0]);
        st_u64_agent(dst + 1, src[1]);
      }
      __syncthreads();                          // drain
      if (th == 0) st_u32_agent(Af + i * 16, (u32)(t + 1));
      if (t < 63) {
        wait16<1>(Af, (u32)(t + 1), th);
        EARLY(t + 1);
      }
    }
  } else if (bk >= 32 && bk < 48) {
    // ================= dec-LSTM: block j owns row-tiles [j*16, j*16+16) =======
    const int j = bk - 32;
    const char* wfd = wsb + OFF_WFD;
    const int tI0 = j * 16 + w * 2;
    float bD[2][4], cD2[2] = {0.f, 0.f};
    {
      const float* bd = (const float*)(wsb + OFF_BD);
#pragma unroll
      for (int pq = 0; pq < 2; ++pq) {
        int idx = l * 2 + pq, lu = idx >> 4;
        int u = j * 64 + w * 8 + lu;
#pragma unroll
        for (int g = 0; g < 4; ++g) bD[pq][g] = bd[g * 1024 + u];
      }
    }
    for (int t = 1; t <= 64; ++t) {
      wait16<2>(Af, (u32)t, th);
      wait16<2>(Bf, (u32)t, th);
      if (t >= 2) wait16<2>(Df, (u32)(t - 1), th);
      f32x4 acc0 = {0.f, 0.f, 0.f, 0.f}, acc1 = {0.f, 0.f, 0.f, 0.f};
      for (int s = 0; s < 80; ++s) {
        const char* bsrc;
        if (s < 32)      bsrc = wsb + OFF_AHFD + (((size_t)t * 32 + s) * 64 + l) * 16;
        else if (s < 48) bsrc = wsb + OFF_CTXFD + (((size_t)t * 16 + (s - 32)) * 64 + l) * 16;
        else             bsrc = wsb + OFF_DHFD + (((size_t)(t - 1) * 32 + (s - 48)) * 64 + l) * 16;
        short8 bv = ld_frag_nt(bsrc);
        short8 a0 = ld_frag_nt(wfd + (((size_t)tI0 * 80 + s) * 64 + l) * 16);
        short8 a1 = ld_frag_nt(wfd + (((size_t)(tI0 + 1) * 80 + s) * 64 + l) * 16);
        acc0 = __builtin_amdgcn_mfma_f32_16x16x32_bf16(a0, bv, acc0, 0, 0, 0);
        acc1 = __builtin_amdgcn_mfma_f32_16x16x32_bf16(a1, bv, acc1, 0, 0, 0);
      }
      {
        float* myW = smW + w * 512;
#pragma unroll
        for (int r4 = 0; r4 < 4; ++r4) {
          myW[((l >> 4) * 4 + r4) * 16 + (l & 15)] = acc0[r4];
          myW[256 + ((l >> 4) * 4 + r4) * 16 + (l & 15)] = acc1[r4];
        }
      }
      __syncthreads();
      {
        const float* myW = smW + w * 512;
        u16* myP = sp + w * 128;
        float* dhf = (float*)(wsb + OFF_DHF);
#pragma unroll
        for (int pq = 0; pq < 2; ++pq) {
          int idx = l * 2 + pq, lu = idx >> 4, b = idx & 15;
          int rt = lu >> 2, uoff = lu & 3;
          float gi = myW[rt * 256 + (0 * 4 + uoff) * 16 + b] + bD[pq][0];
          float gf = myW[rt * 256 + (1 * 4 + uoff) * 16 + b] + bD[pq][1];
          float gg = myW[rt * 256 + (2 * 4 + uoff) * 16 + b] + bD[pq][2];
          float go = myW[rt * 256 + (3 * 4 + uoff) * 16 + b] + bD[pq][3];
          float c2 = sigmf(gf) * cD2[pq] + sigmf(gi) * tanhf(gg);
          float h2 = sigmf(go) * tanhf(c2);
          cD2[pq] = c2;
          int u = j * 64 + w * 8 + lu;
          st_f32_agent(dhf + ((size_t)t * 1024 + u) * 16 + b, h2);
          myP[b * 8 + lu] = f2bf(h2);
        }
      }
      __syncthreads();
      if (l < 16) {
        const u64* src = (const u64*)(sp + w * 128) + l * 2;
        int slab = j * 8 + w;
        u64* dst = (u64*)(wsb + OFF_DHFD + ((size_t)t * 32 + (slab >> 2)) * 1024 +
                          ((size_t)((slab & 3) * 16 + l)) * 16);
        st_u64_agent(dst, src[0]);
        st_u64_agent(dst + 1, src[1]);
      }
      __syncthreads();
      if (th == 0) st_u32_agent(Df + j * 16, (u32)t);
    }
  } else if (bk < 16) {
    // ================= phase-B: conv + query + energies + softmax + ctx =======
    const int b = bk;
    for (int t = 0; t < 64; ++t) {
      {  // conv(t) -> bf16 A-frags
        int jmax = (lenB + 15) >> 4;
        for (int jj = 0; jj < jmax; ++jj) {
          int idx = jj * 512 + th, tt = idx >> 5, f = idx & 31;
          float a = 0.f;
          const float* w0 = s1cw + f * 62;
#pragma unroll
          for (int kk = 0; kk < 31; ++kk) {
            int pos = tt + kk - 15;
            bool ok = (pos >= 0 && pos < 256);
            float awv = ok ? s_aw[pos] : 0.f;
            float awcv = ok ? s_awc[pos] : 0.f;
            a += awv * w0[kk] + awcv * w0[31 + kk];
          }
          s_convF[(tt >> 4) * 512 + ((f >> 3) * 16 + (tt & 15)) * 8 + (f & 7)] = f2bf(a);
        }
      }
      wait16<1>(Af, (u32)(t + 1), th);          // ah(t) published
      {  // query via MFMA
        f32x4 qacc = {0.f, 0.f, 0.f, 0.f};
        const char* qwf = wsb + OFF_QWF;
#pragma unroll 4
        for (int kt = 0; kt < 32; ++kt) {
          short8 av = *(const short8*)(qwf + (((size_t)w * 32 + kt) * 64 + l) * 16);
          short8 bv = ld_frag(wsb + OFF_AHFD + ((size_t)(t + 1) * 32 + kt) * 1024 +
                              ((size_t)(l >> 4) * 16 + b) * 16);
          qacc = __builtin_amdgcn_mfma_f32_16x16x32_bf16(av, bv, qacc, 0, 0, 0);
        }
        if ((l & 15) == 0) {
          int r0 = (l >> 4) * 4;
          s2q[w * 16 + r0]     = qacc[0];
          s2q[w * 16 + r0 + 1] = qacc[1];
          s2q[w * 16 + r0 + 2] = qacc[2];
          s2q[w * 16 + r0 + 3] = qacc[3];
        }
      }
      __syncthreads();
      {  // energies via MFMA
#pragma unroll
        for (int tl = 0; tl < 2; ++tl) {
          int ttile = w * 2 + tl;
          short8 afc = *(const short8*)&s_convF[ttile * 512 + l * 8];
          int dcol = l & 15;
          float e0 = 0.f, e1 = 0.f, e2 = 0.f, e3 = 0.f;
          const float* pmb = pm + ((size_t)(b * 256 + ttile * 16 + (l >> 4) * 4)) * 128 + dcol;
#pragma unroll
          for (int dt = 0; dt < 8; ++dt) {
            f32x4 S = {0.f, 0.f, 0.f, 0.f};
            S = __builtin_amdgcn_mfma_f32_16x16x32_bf16(afc, ldwB[dt], S, 0, 0, 0);
            int d = dt * 16 + dcol;
            float qd = s2q[d], vd = s2v[d];
            e0 += vd * tanh_fast(qd + pmb[dt * 16 + 0 * 128] + S[0]);
            e1 += vd * tanh_fast(qd + pmb[dt * 16 + 1 * 128] + S[1]);
            e2 += vd * tanh_fast(qd + pmb[dt * 16 + 2 * 128] + S[2]);
            e3 += vd * tanh_fast(qd + pmb[dt * 16 + 3 * 128] + S[3]);
          }
#pragma unroll
          for (int off = 8; off; off >>= 1) {
            e0 += __shfl_xor(e0, off);
            e1 += __shfl_xor(e1, off);
            e2 += __shfl_xor(e2, off);
            e3 += __shfl_xor(e3, off);
          }
          if ((l & 15) == 0) {
            int tb0 = ttile * 16 + (l >> 4) * 4;
            s_e[tb0]     = (tb0     < lenB) ? __expf(e0) : 0.f;
            s_e[tb0 + 1] = (tb0 + 1 < lenB) ? __expf(e1) : 0.f;
            s_e[tb0 + 2] = (tb0 + 2 < lenB) ? __expf(e2) : 0.f;
            s_e[tb0 + 3] = (tb0 + 3 < lenB) ? __expf(e3) : 0.f;
          }
        }
      }
      __syncthreads();
      if (th < 256) {
        float v0 = s_e[th];
#pragma unroll
        for (int off = 32; off; off >>= 1) v0 += __shfl_xor(v0, off);
        if ((th & 63) == 0) s3wr[th >> 6] = v0;
      }
      __syncthreads();
      float rden = 1.f / (s3wr[0] + s3wr[1] + s3wr[2] + s3wr[3]);
      if (th < 256) {
        float a = s_e[th] * rden;
        s_aw[th] = a;
        s_awc[th] += a;
        p.out[82944 + ((size_t)(b * 64 + t)) * 256 + th] = a;
      }
      __syncthreads();
      {  // context
        int dq = th & 127, tg = th >> 7;
        int d0 = dq * 4;
        float a0 = 0.f, a1 = 0.f, a2 = 0.f, a3 = 0.f;
        const float* mb = p.memory + ((size_t)b * 256) * 512 + d0;
        for (int tt = tg; tt < lenB; tt += 4) {
          float4 mv = *(const float4*)(mb + (size_t)tt * 512);
          float aw = s_aw[tt];
          a0 += aw * mv.x; a1 += aw * mv.y; a2 += aw * mv.z; a3 += aw * mv.w;
        }
        smC[tg * 512 + d0]     = a0;
        smC[tg * 512 + d0 + 1] = a1;
        smC[tg * 512 + d0 + 2] = a2;
        smC[tg * 512 + d0 + 3] = a3;
      }
      __syncthreads();
      {
        int d = th;
        float ctxv = smC[d] + smC[512 + d] + smC[1024 + d] + smC[1536 + d];
        st_f32_agent((float*)(wsb + OFF_CTXF) + (size_t)(t + 1) * 8192 + b * 512 + d, ctxv);
        s_pack[d] = f2bf(ctxv);
      }
      __syncthreads();
      if (th < 64) {  // coalesced CTXFD publish
        u64 p0 = ((const u64*)s_pack)[th * 2];
        u64 p1 = ((const u64*)s_pack)[th * 2 + 1];
        u64* dst = (u64*)(wsb + OFF_CTXFD + ((size_t)(t + 1) * 16 + (th >> 2)) * 1024 +
                          ((size_t)(th & 3) * 16 + b) * 16);
        st_u64_agent(dst, p0);
        st_u64_agent(dst + 1, p1);
      }
      __syncthreads();
      if (th == 0) st_u32_agent(Bf + b * 16, (u32)(t + 1));
    }
  }

  // ================= final dataflow sync + epilogue =================
  if (bk >= 48) {
    wait16<64>(Df, 64u, th);
    wait16<64>(Bf, 64u, th);
  } else {
    wait16<4>(Df, 64u, th);
    wait16<4>(Bf, 64u, th);
  }
  {
    int t = bk & 63, pa = bk >> 6;
    const float* dh = (const float*)(wsb + OFF_DHF) + (size_t)(t + 1) * 16384;
    const float* cxt = (const float*)(wsb + OFF_CTXF) + (size_t)(t + 1) * 8192;
    int lim = (pa == 3) ? 336 : 320;
    for (int idx = th; idx < lim; idx += 512) {
      if (idx < 320) {
        int mi = idx >> 4, b = idx & 15, m = pa * 20 + mi;
        const float* wr = p.projW + (size_t)m * 1536;
        const float* cxb = cxt + b * 512;
        float a0 = 0.f, a1 = 0.f;
#pragma unroll 8
        for (int k = 0; k < 1024; k += 2) { a0 += wr[k] * dh[k * 16 + b]; a1 += wr[k + 1] * dh[(k + 1) * 16 + b]; }
#pragma unroll 8
        for (int k = 0; k < 512; k += 2)  { a0 += wr[1024 + k] * cxb[k]; a1 += wr[1025 + k] * cxb[k + 1]; }
        p.out[((size_t)(b * 80 + m)) * 64 + t] = a0 + a1 + p.projb[m];
      } else {
        int b = idx - 320;
        const float* cxb = cxt + b * 512;
        float a0 = 0.f, a1 = 0.f;
#pragma unroll 8
        for (int k = 0; k < 1024; k += 2) { a0 += p.gateW[k] * dh[k * 16 + b]; a1 += p.gateW[k + 1] * dh[(k + 1) * 16 + b]; }
#pragma unroll 8
        for (int k = 0; k < 512; k += 2)  { a0 += p.gateW[1024 + k] * cxb[k]; a1 += p.gateW[1025 + k] * cxb[k + 1]; }
        p.out[81920 + b * 64 + t] = a0 + a1 + p.gateb[0];
      }
    }
  }
}

// ---------------- host launcher ----------------
extern "C" void kernel_launch(void* const* d_in, const int* in_sizes, int n_in,
                              void* d_out, int out_size, void* d_ws, size_t ws_size,
                              hipStream_t stream) {
  (void)in_sizes; (void)n_in; (void)out_size; (void)ws_size;
  const float* memory = (const float*)d_in[0];
  const float* dec_in = (const float*)d_in[1];
  const int*   mlen   = (const int*)d_in[2];
  const float* pW1    = (const float*)d_in[3];
  const float* pb1    = (const float*)d_in[4];
  const float* pW2    = (const float*)d_in[5];
  const float* pb2    = (const float*)d_in[6];
  const float* aWih   = (const float*)d_in[7];
  const float* aWhh   = (const float*)d_in[8];
  const float* abih   = (const float*)d_in[9];
  const float* abhh   = (const float*)d_in[10];
  const float* qW     = (const float*)d_in[11];
  const float* memW   = (const float*)d_in[12];
  const float* convW  = (const float*)d_in[13];
  const float* ldW    = (const float*)d_in[14];
  const float* attnv  = (const float*)d_in[15];
  const float* dWih   = (const float*)d_in[16];
  const float* dWhh   = (const float*)d_in[17];
  const float* dbih   = (const float*)d_in[18];
  const float* dbhh   = (const float*)d_in[19];
  const float* projW  = (const float*)d_in[20];
  const float* projb  = (const float*)d_in[21];
  const float* gateW  = (const float*)d_in[22];
  const float* gateb  = (const float*)d_in[23];
  char* wsb = (char*)d_ws;
  float* out = (float*)d_out;

  // zero slot-0 fragments (initial states) + flag words (replay-safe)
  hipMemsetAsync(wsb + OFF_AHFD, 0, 32768, stream);
  hipMemsetAsync(wsb + OFF_CTXFD, 0, 16384, stream);
  hipMemsetAsync(wsb + OFF_DHFD, 0, 32768, stream);
  hipMemsetAsync(wsb + OFF_BAR, 0, 4096, stream);

  hipLaunchKernelGGL(k_wfrag, dim3(3584), dim3(256), 0, stream, aWih, aWhh, wsb + OFF_WFA, 56, 768);
  hipLaunchKernelGGL(k_wfrag, dim3(5120), dim3(256), 0, stream, dWih, dWhh, wsb + OFF_WFD, 80, 1536);
  hipLaunchKernelGGL(k_qwfrag, dim3(64), dim3(256), 0, stream, qW, wsb + OFF_QWF);
  hipLaunchKernelGGL(k_smallprep, dim3(288), dim3(256), 0, stream, memW, abih, abhh, dbih, dbhh, wsb);
  hipLaunchKernelGGL(k_prenet, dim3(64, 16), dim3(256), 0, stream, dec_in, pW1, pb1, pW2, pb2, wsb);
  hipLaunchKernelGGL(k_pm, dim3(256), dim3(256), 0, stream, memory, wsb);

  KParams p{memory, mlen, convW, ldW, attnv, projW, projb, gateW, gateb, wsb, out};
  void* args[] = { &p };
  hipLaunchCooperativeKernel((void*)k_main, dim3(256), dim3(512), args, 0, stream);
}

// Round 16
// 2879.448 us; speedup vs baseline: 1.1043x; 1.1043x over previous
//
#include <hip/hip_runtime.h>

typedef __attribute__((ext_vector_type(8))) short short8;
typedef __attribute__((ext_vector_type(4))) float f32x4;
typedef unsigned short u16;
typedef unsigned int u32;
typedef unsigned long long u64;

// Shapes: B=16, T_ENC=256, T_DEC=64, N_MEL=80, ENC=512, ARNN=DRNN=1024,
// PRENET=256, ATTN_DIM=128, LOC_F=32, LOC_K=31
// attn LSTM K = 1792 (56 tiles of 32); dec K = 2560 (80 tiles)
// MFMA 16x16x32 bf16; C/D: col=lane&15, row=(lane>>4)*4+reg  [HW-verified]
//
// r16 = r15 structure minus the poison: dec uses PLAIN cached loads (r15's
// NT streaming of 20MB/step of dec weights caused the 651MB FETCH + regression).
// 32 attn blocks + 32 dec blocks (1 rowtile/wave, full K -> no cross-wave
// reduction), 16 phase-B blocks. Direct 16/32-line flag polls, no aggregators.
// Coherence: writes agent-scope (LLC); reads plain cached on step-versioned
// virgin addresses (flag-gated; stale lines impossible; replay-safe).

// ---------------- workspace byte offsets ----------------
static constexpr size_t OFF_WFA   = 0;                 // 14,680,064
static constexpr size_t OFF_WFD   = 14680064;          // +20,971,520 = 35,651,584
static constexpr size_t OFF_PREF  = 35651584;          // +524,288
static constexpr size_t OFF_QWF   = 36175872;          // +262,144  qW A-frags
static constexpr size_t OFF_MWT   = 36438016;          // +262,144
static constexpr size_t OFF_BA    = 36700160;          // +16,384
static constexpr size_t OFF_BD    = 36716544;          // +16,384
static constexpr size_t OFF_PM    = 36732928;          // +2,097,152  pm[b][tt][d] f32
static constexpr size_t OFF_CTXF  = 38830080;          // +2,129,920  [t][b][d] f32
static constexpr size_t OFF_DHF   = 40960000;          // +4,259,840  [t][u][b] f32
static constexpr size_t OFF_AHFD  = 45219840;          // +2,129,920  65 x 32KB frag
static constexpr size_t OFF_CTXFD = 47349760;          // +1,064,960  65 x 16KB frag
static constexpr size_t OFF_DHFD  = 48414720;          // +2,129,920  65 x 32KB frag
static constexpr size_t OFF_BAR   = 50544640;          // Af@0(2KB) Df@2048(2KB) Bf@4096(1KB)
static constexpr size_t OFF_END   = 50552832;

__device__ __forceinline__ float sigmf(float x) { return 1.f / (1.f + expf(-x)); }
__device__ __forceinline__ float tanh_fast(float x) {
  float e2 = __expf(2.f * x);
  return 1.f - 2.f / (e2 + 1.f);
}
__device__ __forceinline__ u16 f2bf(float f) {
  u32 u = __float_as_uint(f);
  return (u16)((u + 0x7FFFu + ((u >> 16) & 1u)) >> 16);
}
__device__ __forceinline__ float bf2f(u16 x) { return __uint_as_float(((u32)x) << 16); }

__device__ __forceinline__ short8 ld_frag(const void* p) {
  return *(const short8*)p;
}

// agent-scope helpers (UC path)
__device__ __forceinline__ void st_u16_agent(u16* p, u16 v) {
  __hip_atomic_store(p, v, __ATOMIC_RELAXED, __HIP_MEMORY_SCOPE_AGENT);
}
__device__ __forceinline__ void st_f32_agent(float* p, float v) {
  __hip_atomic_store(p, v, __ATOMIC_RELAXED, __HIP_MEMORY_SCOPE_AGENT);
}
__device__ __forceinline__ void st_u64_agent(u64* p, u64 v) {
  __hip_atomic_store(p, v, __ATOMIC_RELAXED, __HIP_MEMORY_SCOPE_AGENT);
}
__device__ __forceinline__ u32 ld_u32_agent(const u32* p) {
  return __hip_atomic_load(p, __ATOMIC_RELAXED, __HIP_MEMORY_SCOPE_AGENT);
}
__device__ __forceinline__ void st_u32_agent(u32* p, u32 v) {
  __hip_atomic_store(p, v, __ATOMIC_RELAXED, __HIP_MEMORY_SCOPE_AGENT);
}

// waits: one wave polls N strided lines, then block barrier
template <int SLP>
__device__ __forceinline__ void wait16(const u32* F, u32 target, int th) {
  if (th < 64) {
    const u32* pf = F + (th & 15) * 16;
    for (;;) {
      u32 v = ld_u32_agent(pf);
      if (__all(v >= target)) break;
      __builtin_amdgcn_s_sleep(SLP);
    }
  }
  __syncthreads();
}
template <int SLP>
__device__ __forceinline__ void wait32(const u32* F, u32 target, int th) {
  if (th < 64) {
    const u32* pf = F + (th & 31) * 16;
    for (;;) {
      u32 v = ld_u32_agent(pf);
      if (__all(v >= target)) break;
      __builtin_amdgcn_s_sleep(SLP);
    }
  }
  __syncthreads();
}

// ---------------- prep: LSTM weights -> bf16 A-fragment layout ----------------
__global__ void k_wfrag(const float* __restrict__ Wih, const float* __restrict__ Whh,
                        char* __restrict__ dst, int NT, int Kih) {
  int idx = blockIdx.x * 256 + threadIdx.x;   // (tile*NT + s)*64 + l
  int l = idx & 63;
  int st = idx >> 6;
  int s = st % NT, tile = st / NT;
  int r = l & 15, kg = l >> 4;
  int j = (r >> 2) * 1024 + tile * 4 + (r & 3);
  int k0 = s * 32 + kg * 8;
  const float* src = (k0 < Kih) ? (Wih + (size_t)j * Kih + k0)
                                : (Whh + (size_t)j * 1024 + (k0 - Kih));
  short8 v;
#pragma unroll
  for (int e = 0; e < 8; ++e) v[e] = (short)f2bf(src[e]);
  *(short8*)(dst + (size_t)idx * 16) = v;
}

// ---------------- prep: qW -> bf16 A-fragments (8 d-tiles x 32 k-tiles) -------
__global__ void k_qwfrag(const float* __restrict__ qW, char* __restrict__ dst) {
  int idx = blockIdx.x * 256 + threadIdx.x;   // tile*64 + l, 16384 total
  int l = idx & 63, tile = idx >> 6;
  int dt = tile >> 5, kt = tile & 31;
  int j = dt * 16 + (l & 15);
  int k0 = kt * 32 + (l >> 4) * 8;
  short8 v;
#pragma unroll
  for (int e = 0; e < 8; ++e) v[e] = (short)f2bf(qW[j * 1024 + k0 + e]);
  *(short8*)(dst + (size_t)idx * 16) = v;
}

// ---------------- prep: memW^T, combined biases ----------------
__global__ void k_smallprep(const float* __restrict__ memW,
                            const float* __restrict__ abih, const float* __restrict__ abhh,
                            const float* __restrict__ dbih, const float* __restrict__ dbhh,
                            char* __restrict__ wsb) {
  int idx = blockIdx.x * 256 + threadIdx.x;
  if (idx < 65536) {
    int k = idx >> 7, d = idx & 127;
    ((float*)(wsb + OFF_MWT))[idx] = memW[d * 512 + k];
  } else if (idx < 69632) {
    int j = idx - 65536;
    ((float*)(wsb + OFF_BA))[j] = abih[j] + abhh[j];
  } else if (idx < 73728) {
    int j = idx - 69632;
    ((float*)(wsb + OFF_BD))[j] = dbih[j] + dbhh[j];
  }
}

// ---------------- prep: prenet -> bf16 B-fragment layout per step ----------------
__global__ void k_prenet(const float* __restrict__ dec_in,
                         const float* __restrict__ W1, const float* __restrict__ b1,
                         const float* __restrict__ W2, const float* __restrict__ b2,
                         char* __restrict__ wsb) {
  int s = blockIdx.x, b = blockIdx.y, th = threadIdx.x;
  __shared__ float frame[80];
  __shared__ float h1[256];
  if (th < 80) frame[th] = (s == 0) ? 0.f : dec_in[(b * 80 + th) * 64 + (s - 1)];
  __syncthreads();
  float a = b1[th];
  const float* w1r = W1 + th * 80;
  for (int m = 0; m < 80; ++m) a += w1r[m] * frame[m];
  h1[th] = fmaxf(a, 0.f);
  __syncthreads();
  float a2 = b2[th];
  const float* w2r = W2 + th * 256;
  for (int i = 0; i < 256; ++i) a2 += w2r[i] * h1[i];
  float pre = fmaxf(a2, 0.f);
  int k = th;
  ((u16*)(wsb + OFF_PREF))[(((size_t)s * 8 + (k >> 5)) * 64 + ((k >> 3) & 3) * 16 + b) * 8 + (k & 7)] = f2bf(pre);
}

// ---------------- prep: processed_memory pm[b][tt][d] ----------------
__global__ void k_pm(const float* __restrict__ memory, char* __restrict__ wsb) {
  int bk = blockIdx.x, th = threadIdx.x;
  int b = bk >> 4, t0 = (bk & 15) * 16;
  __shared__ float mrow[16 * 512];
  for (int i = 0; i < 8; ++i) {
    int fi4 = i * 256 + th;
    int tl = fi4 >> 7, k4 = (fi4 & 127) << 2;
    *(float4*)&mrow[tl * 512 + k4] =
        *(const float4*)&memory[((size_t)(b * 256 + t0 + tl)) * 512 + k4];
  }
  __syncthreads();
  int d = th & 127, tl0 = th >> 7;
  float acc[8] = {};
  const float* mWT = (const float*)(wsb + OFF_MWT);
  float* pmw = (float*)(wsb + OFF_PM);
  for (int k = 0; k < 512; ++k) {
    float w = mWT[k * 128 + d];
#pragma unroll
    for (int i = 0; i < 8; ++i) acc[i] += w * mrow[(tl0 + i * 2) * 512 + k];
  }
  for (int i = 0; i < 8; ++i)
    pmw[((size_t)(b * 256 + t0 + tl0 + i * 2)) * 128 + d] = acc[i];
}

struct KParams {
  const float* memory;
  const int* mlen;
  const float* convW;
  const float* ldW;
  const float* attnv;
  const float* projW;
  const float* projb;
  const float* gateW;
  const float* gateb;
  char* wsb;
  float* out;
};

// ---------------- main persistent kernel ----------------
// Roles: bk 0..15 phase-B(b); bk 16..47 attn-LSTM (8 rowtiles, 1/wave);
//        bk 48..79 dec-LSTM (8 rowtiles, 1/wave, plain loads); bk 80..255 idle.
__global__ void __launch_bounds__(512, 1) k_main(KParams p) {
  const int th = threadIdx.x;
  const int bk = blockIdx.x;
  char* wsb = p.wsb;
  const int l = th & 63, w = th >> 6;
  u32* Af = (u32*)(wsb + OFF_BAR);            // 32 strided lines
  u32* Df = (u32*)(wsb + OFF_BAR + 2048);     // 32 strided lines
  u32* Bf = (u32*)(wsb + OFF_BAR + 4096);     // 16 strided lines

  __shared__ float smC[4608];
  __shared__ float s2q[128], s2v[128];
  __shared__ u16 s_convF[8192];
  __shared__ u16 s_pack[512];
  __shared__ float s_e[256], s3wr[4];
  __shared__ float s1cw[1984];
  __shared__ float s_aw[256], s_awc[256];
  __shared__ float smW[2048];                 // 8 waves x 256 gate slab
  __shared__ u16 sp[512];                     // 8 waves x 64 pack

  const float* pm = (const float*)(wsb + OFF_PM);

  if (bk < 16) {
    for (int i = th; i < 1984; i += 512) s1cw[i] = p.convW[i];
    for (int i = th; i < 4096; i += 512) ((u32*)s_convF)[i] = 0u;
    if (th < 128) s2v[th] = p.attnv[th];
    if (th < 256) { s_aw[th] = 0.f; s_awc[th] = 0.f; }
  }
  int lenB = 0;
  if (bk < 16) lenB = p.mlen[bk];

  short8 ldwB[8];
  if (bk < 16) {
    int kg = l >> 4, dcol = l & 15;
#pragma unroll
    for (int dt = 0; dt < 8; ++dt) {
      short8 v;
#pragma unroll
      for (int e = 0; e < 8; ++e)
        v[e] = (short)f2bf(p.ldW[(dt * 16 + dcol) * 32 + kg * 8 + e]);
      ldwB[dt] = v;
    }
  }
  __syncthreads();

  if (bk >= 16 && bk < 48) {
    // ========== attn-LSTM: block i owns rowtiles [i*8, i*8+8), wave = 1 =======
    const int i = bk - 16;
    const char* wfa = wsb + OFF_WFA;
    const int tI = i * 8 + w;                   // this wave's rowtile
    const int ul = l >> 4, b = l & 15;          // lane's (unit-offset, batch)
    float bA[4], cA = 0.f;
    {
      const float* ba = (const float*)(wsb + OFF_BA);
      int u = tI * 4 + ul;
#pragma unroll
      for (int g = 0; g < 4; ++g) bA[g] = ba[g * 1024 + u];
    }
    f32x4 acc;
    auto EARLY = [&](int t) {
      acc = f32x4{0.f, 0.f, 0.f, 0.f};
      for (int e = 0; e < 40; ++e) {
        int s = (e < 8) ? e : (24 + (e - 8));
        const char* bsrc = (e < 8)
            ? wsb + OFF_PREF + (((size_t)t * 8 + s) * 64 + l) * 16
            : wsb + OFF_AHFD + (((size_t)t * 32 + (s - 24)) * 64 + l) * 16;
        short8 bv = ld_frag(bsrc);
        short8 av = *(const short8*)(wfa + (((size_t)tI * 56 + s) * 64 + l) * 16);
        acc = __builtin_amdgcn_mfma_f32_16x16x32_bf16(av, bv, acc, 0, 0, 0);
      }
    };
    EARLY(0);
    for (int t = 0; t < 64; ++t) {
      wait16<1>(Bf, (u32)t, th);                // ctx(t-1) ready
#pragma unroll
      for (int s = 8; s < 24; ++s) {            // late: CTXFD K-tiles
        short8 bv = ld_frag(wsb + OFF_CTXFD + (((size_t)t * 16 + (s - 8)) * 64 + l) * 16);
        short8 av = *(const short8*)(wfa + (((size_t)tI * 56 + s) * 64 + l) * 16);
        acc = __builtin_amdgcn_mfma_f32_16x16x32_bf16(av, bv, acc, 0, 0, 0);
      }
      {
        float* myW = smW + w * 256;
#pragma unroll
        for (int r4 = 0; r4 < 4; ++r4)
          myW[((l >> 4) * 4 + r4) * 16 + (l & 15)] = acc[r4];
      }
      __syncthreads();
      {  // pointwise: lane owns (ul, b)
        const float* myW = smW + w * 256;
        u16* myP = sp + w * 64;
        float gi = myW[(0 * 4 + ul) * 16 + b] + bA[0];
        float gf = myW[(1 * 4 + ul) * 16 + b] + bA[1];
        float gg = myW[(2 * 4 + ul) * 16 + b] + bA[2];
        float go = myW[(3 * 4 + ul) * 16 + b] + bA[3];
        float c2 = sigmf(gf) * cA + sigmf(gi) * tanhf(gg);
        float h2 = sigmf(go) * tanhf(c2);
        cA = c2;
        myP[b * 4 + ul] = f2bf(h2);
      }
      __syncthreads();
      if (l < 16) {  // publish half-octet: u = tI*4..tI*4+3 for batch l
        u64 val = ((const u64*)(sp + w * 64))[l];
        u64* dst = (u64*)(wsb + OFF_AHFD + ((size_t)(t + 1) * 32 + (tI >> 3)) * 1024 +
                          ((size_t)(((tI >> 1) & 3) * 16 + l)) * 16 + (size_t)(tI & 1) * 8);
        st_u64_agent(dst, val);
      }
      __syncthreads();                          // drain
      if (th == 0) st_u32_agent(Af + i * 16, (u32)(t + 1));
      if (t < 63) {
        wait32<1>(Af, (u32)(t + 1), th);
        EARLY(t + 1);
      }
    }
  } else if (bk >= 48 && bk < 80) {
    // ========== dec-LSTM: block j owns rowtiles [j*8, j*8+8), wave = 1 ========
    const int j = bk - 48;
    const char* wfd = wsb + OFF_WFD;
    const int tI = j * 8 + w;
    const int ul = l >> 4, b = l & 15;
    float bD[4], cD = 0.f;
    {
      const float* bd = (const float*)(wsb + OFF_BD);
      int u = tI * 4 + ul;
#pragma unroll
      for (int g = 0; g < 4; ++g) bD[g] = bd[g * 1024 + u];
    }
    for (int t = 1; t <= 64; ++t) {
      wait32<2>(Af, (u32)t, th);
      wait16<2>(Bf, (u32)t, th);
      if (t >= 2) wait32<2>(Df, (u32)(t - 1), th);
      f32x4 acc = {0.f, 0.f, 0.f, 0.f};
      for (int s = 0; s < 80; ++s) {
        const char* bsrc;
        if (s < 32)      bsrc = wsb + OFF_AHFD + (((size_t)t * 32 + s) * 64 + l) * 16;
        else if (s < 48) bsrc = wsb + OFF_CTXFD + (((size_t)t * 16 + (s - 32)) * 64 + l) * 16;
        else             bsrc = wsb + OFF_DHFD + (((size_t)(t - 1) * 32 + (s - 48)) * 64 + l) * 16;
        short8 bv = ld_frag(bsrc);
        short8 av = *(const short8*)(wfd + (((size_t)tI * 80 + s) * 64 + l) * 16);
        acc = __builtin_amdgcn_mfma_f32_16x16x32_bf16(av, bv, acc, 0, 0, 0);
      }
      {
        float* myW = smW + w * 256;
#pragma unroll
        for (int r4 = 0; r4 < 4; ++r4)
          myW[((l >> 4) * 4 + r4) * 16 + (l & 15)] = acc[r4];
      }
      __syncthreads();
      {
        const float* myW = smW + w * 256;
        u16* myP = sp + w * 64;
        float gi = myW[(0 * 4 + ul) * 16 + b] + bD[0];
        float gf = myW[(1 * 4 + ul) * 16 + b] + bD[1];
        float gg = myW[(2 * 4 + ul) * 16 + b] + bD[2];
        float go = myW[(3 * 4 + ul) * 16 + b] + bD[3];
        float c2 = sigmf(gf) * cD + sigmf(gi) * tanhf(gg);
        float h2 = sigmf(go) * tanhf(c2);
        cD = c2;
        int u = tI * 4 + ul;
        st_f32_agent((float*)(wsb + OFF_DHF) + ((size_t)t * 1024 + u) * 16 + b, h2);
        myP[b * 4 + ul] = f2bf(h2);
      }
      __syncthreads();
      if (l < 16) {
        u64 val = ((const u64*)(sp + w * 64))[l];
        u64* dst = (u64*)(wsb + OFF_DHFD + ((size_t)t * 32 + (tI >> 3)) * 1024 +
                          ((size_t)(((tI >> 1) & 3) * 16 + l)) * 16 + (size_t)(tI & 1) * 8);
        st_u64_agent(dst, val);
      }
      __syncthreads();
      if (th == 0) st_u32_agent(Df + j * 16, (u32)t);
    }
  } else if (bk < 16) {
    // ========== phase-B: conv + query + energies + softmax + ctx ==============
    const int b = bk;
    for (int t = 0; t < 64; ++t) {
      {  // conv(t) -> bf16 A-frags
        int jmax = (lenB + 15) >> 4;
        for (int jj = 0; jj < jmax; ++jj) {
          int idx = jj * 512 + th, tt = idx >> 5, f = idx & 31;
          float a = 0.f;
          const float* w0 = s1cw + f * 62;
#pragma unroll
          for (int kk = 0; kk < 31; ++kk) {
            int pos = tt + kk - 15;
            bool ok = (pos >= 0 && pos < 256);
            float awv = ok ? s_aw[pos] : 0.f;
            float awcv = ok ? s_awc[pos] : 0.f;
            a += awv * w0[kk] + awcv * w0[31 + kk];
          }
          s_convF[(tt >> 4) * 512 + ((f >> 3) * 16 + (tt & 15)) * 8 + (f & 7)] = f2bf(a);
        }
      }
      wait32<1>(Af, (u32)(t + 1), th);          // ah(t) published
      {  // query via MFMA
        f32x4 qacc = {0.f, 0.f, 0.f, 0.f};
        const char* qwf = wsb + OFF_QWF;
#pragma unroll 4
        for (int kt = 0; kt < 32; ++kt) {
          short8 av = *(const short8*)(qwf + (((size_t)w * 32 + kt) * 64 + l) * 16);
          short8 bv = ld_frag(wsb + OFF_AHFD + ((size_t)(t + 1) * 32 + kt) * 1024 +
                              ((size_t)(l >> 4) * 16 + b) * 16);
          qacc = __builtin_amdgcn_mfma_f32_16x16x32_bf16(av, bv, qacc, 0, 0, 0);
        }
        if ((l & 15) == 0) {
          int r0 = (l >> 4) * 4;
          s2q[w * 16 + r0]     = qacc[0];
          s2q[w * 16 + r0 + 1] = qacc[1];
          s2q[w * 16 + r0 + 2] = qacc[2];
          s2q[w * 16 + r0 + 3] = qacc[3];
        }
      }
      __syncthreads();
      {  // energies via MFMA
#pragma unroll
        for (int tl = 0; tl < 2; ++tl) {
          int ttile = w * 2 + tl;
          short8 afc = *(const short8*)&s_convF[ttile * 512 + l * 8];
          int dcol = l & 15;
          float e0 = 0.f, e1 = 0.f, e2 = 0.f, e3 = 0.f;
          const float* pmb = pm + ((size_t)(b * 256 + ttile * 16 + (l >> 4) * 4)) * 128 + dcol;
#pragma unroll
          for (int dt = 0; dt < 8; ++dt) {
            f32x4 S = {0.f, 0.f, 0.f, 0.f};
            S = __builtin_amdgcn_mfma_f32_16x16x32_bf16(afc, ldwB[dt], S, 0, 0, 0);
            int d = dt * 16 + dcol;
            float qd = s2q[d], vd = s2v[d];
            e0 += vd * tanh_fast(qd + pmb[dt * 16 + 0 * 128] + S[0]);
            e1 += vd * tanh_fast(qd + pmb[dt * 16 + 1 * 128] + S[1]);
            e2 += vd * tanh_fast(qd + pmb[dt * 16 + 2 * 128] + S[2]);
            e3 += vd * tanh_fast(qd + pmb[dt * 16 + 3 * 128] + S[3]);
          }
#pragma unroll
          for (int off = 8; off; off >>= 1) {
            e0 += __shfl_xor(e0, off);
            e1 += __shfl_xor(e1, off);
            e2 += __shfl_xor(e2, off);
            e3 += __shfl_xor(e3, off);
          }
          if ((l & 15) == 0) {
            int tb0 = ttile * 16 + (l >> 4) * 4;
            s_e[tb0]     = (tb0     < lenB) ? __expf(e0) : 0.f;
            s_e[tb0 + 1] = (tb0 + 1 < lenB) ? __expf(e1) : 0.f;
            s_e[tb0 + 2] = (tb0 + 2 < lenB) ? __expf(e2) : 0.f;
            s_e[tb0 + 3] = (tb0 + 3 < lenB) ? __expf(e3) : 0.f;
          }
        }
      }
      __syncthreads();
      if (th < 256) {
        float v0 = s_e[th];
#pragma unroll
        for (int off = 32; off; off >>= 1) v0 += __shfl_xor(v0, off);
        if ((th & 63) == 0) s3wr[th >> 6] = v0;
      }
      __syncthreads();
      float rden = 1.f / (s3wr[0] + s3wr[1] + s3wr[2] + s3wr[3]);
      if (th < 256) {
        float a = s_e[th] * rden;
        s_aw[th] = a;
        s_awc[th] += a;
        p.out[82944 + ((size_t)(b * 64 + t)) * 256 + th] = a;
      }
      __syncthreads();
      {  // context
        int dq = th & 127, tg = th >> 7;
        int d0 = dq * 4;
        float a0 = 0.f, a1 = 0.f, a2 = 0.f, a3 = 0.f;
        const float* mb = p.memory + ((size_t)b * 256) * 512 + d0;
        for (int tt = tg; tt < lenB; tt += 4) {
          float4 mv = *(const float4*)(mb + (size_t)tt * 512);
          float aw = s_aw[tt];
          a0 += aw * mv.x; a1 += aw * mv.y; a2 += aw * mv.z; a3 += aw * mv.w;
        }
        smC[tg * 512 + d0]     = a0;
        smC[tg * 512 + d0 + 1] = a1;
        smC[tg * 512 + d0 + 2] = a2;
        smC[tg * 512 + d0 + 3] = a3;
      }
      __syncthreads();
      {
        int d = th;
        float ctxv = smC[d] + smC[512 + d] + smC[1024 + d] + smC[1536 + d];
        st_f32_agent((float*)(wsb + OFF_CTXF) + (size_t)(t + 1) * 8192 + b * 512 + d, ctxv);
        s_pack[d] = f2bf(ctxv);
      }
      __syncthreads();
      if (th < 64) {  // coalesced CTXFD publish
        u64 p0 = ((const u64*)s_pack)[th * 2];
        u64 p1 = ((const u64*)s_pack)[th * 2 + 1];
        u64* dst = (u64*)(wsb + OFF_CTXFD + ((size_t)(t + 1) * 16 + (th >> 2)) * 1024 +
                          ((size_t)(th & 3) * 16 + b) * 16);
        st_u64_agent(dst, p0);
        st_u64_agent(dst + 1, p1);
      }
      __syncthreads();
      if (th == 0) st_u32_agent(Bf + b * 16, (u32)(t + 1));
    }
  }

  // ================= final dataflow sync + epilogue =================
  if (bk >= 80) {
    wait32<64>(Df, 64u, th);
    wait16<64>(Bf, 64u, th);
  } else {
    wait32<4>(Df, 64u, th);
    wait16<4>(Bf, 64u, th);
  }
  {
    int t = bk & 63, pa = bk >> 6;
    const float* dh = (const float*)(wsb + OFF_DHF) + (size_t)(t + 1) * 16384;
    const float* cxt = (const float*)(wsb + OFF_CTXF) + (size_t)(t + 1) * 8192;
    int lim = (pa == 3) ? 336 : 320;
    for (int idx = th; idx < lim; idx += 512) {
      if (idx < 320) {
        int mi = idx >> 4, b = idx & 15, m = pa * 20 + mi;
        const float* wr = p.projW + (size_t)m * 1536;
        const float* cxb = cxt + b * 512;
        float a0 = 0.f, a1 = 0.f;
#pragma unroll 8
        for (int k = 0; k < 1024; k += 2) { a0 += wr[k] * dh[k * 16 + b]; a1 += wr[k + 1] * dh[(k + 1) * 16 + b]; }
#pragma unroll 8
        for (int k = 0; k < 512; k += 2)  { a0 += wr[1024 + k] * cxb[k]; a1 += wr[1025 + k] * cxb[k + 1]; }
        p.out[((size_t)(b * 80 + m)) * 64 + t] = a0 + a1 + p.projb[m];
      } else {
        int b = idx - 320;
        const float* cxb = cxt + b * 512;
        float a0 = 0.f, a1 = 0.f;
#pragma unroll 8
        for (int k = 0; k < 1024; k += 2) { a0 += p.gateW[k] * dh[k * 16 + b]; a1 += p.gateW[k + 1] * dh[(k + 1) * 16 + b]; }
#pragma unroll 8
        for (int k = 0; k < 512; k += 2)  { a0 += p.gateW[1024 + k] * cxb[k]; a1 += p.gateW[1025 + k] * cxb[k + 1]; }
        p.out[81920 + b * 64 + t] = a0 + a1 + p.gateb[0];
      }
    }
  }
}

// ---------------- host launcher ----------------
extern "C" void kernel_launch(void* const* d_in, const int* in_sizes, int n_in,
                              void* d_out, int out_size, void* d_ws, size_t ws_size,
                              hipStream_t stream) {
  (void)in_sizes; (void)n_in; (void)out_size; (void)ws_size;
  const float* memory = (const float*)d_in[0];
  const float* dec_in = (const float*)d_in[1];
  const int*   mlen   = (const int*)d_in[2];
  const float* pW1    = (const float*)d_in[3];
  const float* pb1    = (const float*)d_in[4];
  const float* pW2    = (const float*)d_in[5];
  const float* pb2    = (const float*)d_in[6];
  const float* aWih   = (const float*)d_in[7];
  const float* aWhh   = (const float*)d_in[8];
  const float* abih   = (const float*)d_in[9];
  const float* abhh   = (const float*)d_in[10];
  const float* qW     = (const float*)d_in[11];
  const float* memW   = (const float*)d_in[12];
  const float* convW  = (const float*)d_in[13];
  const float* ldW    = (const float*)d_in[14];
  const float* attnv  = (const float*)d_in[15];
  const float* dWih   = (const float*)d_in[16];
  const float* dWhh   = (const float*)d_in[17];
  const float* dbih   = (const float*)d_in[18];
  const float* dbhh   = (const float*)d_in[19];
  const float* projW  = (const float*)d_in[20];
  const float* projb  = (const float*)d_in[21];
  const float* gateW  = (const float*)d_in[22];
  const float* gateb  = (const float*)d_in[23];
  char* wsb = (char*)d_ws;
  float* out = (float*)d_out;

  // zero slot-0 fragments (initial states) + flag words (replay-safe)
  hipMemsetAsync(wsb + OFF_AHFD, 0, 32768, stream);
  hipMemsetAsync(wsb + OFF_CTXFD, 0, 16384, stream);
  hipMemsetAsync(wsb + OFF_DHFD, 0, 32768, stream);
  hipMemsetAsync(wsb + OFF_BAR, 0, 8192, stream);

  hipLaunchKernelGGL(k_wfrag, dim3(3584), dim3(256), 0, stream, aWih, aWhh, wsb + OFF_WFA, 56, 768);
  hipLaunchKernelGGL(k_wfrag, dim3(5120), dim3(256), 0, stream, dWih, dWhh, wsb + OFF_WFD, 80, 1536);
  hipLaunchKernelGGL(k_qwfrag, dim3(64), dim3(256), 0, stream, qW, wsb + OFF_QWF);
  hipLaunchKernelGGL(k_smallprep, dim3(288), dim3(256), 0, stream, memW, abih, abhh, dbih, dbhh, wsb);
  hipLaunchKernelGGL(k_prenet, dim3(64, 16), dim3(256), 0, stream, dec_in, pW1, pb1, pW2, pb2, wsb);
  hipLaunchKernelGGL(k_pm, dim3(256), dim3(256), 0, stream, memory, wsb);

  KParams p{memory, mlen, convW, ldW, attnv, projW, projb, gateW, gateb, wsb, out};
  void* args[] = { &p };
  hipLaunchCooperativeKernel((void*)k_main, dim3(256), dim3(512), args, 0, stream);
}

// Round 17
// 2772.131 us; speedup vs baseline: 1.1471x; 1.0387x over previous
//
#include <hip/hip_runtime.h>

typedef __attribute__((ext_vector_type(8))) short short8;
typedef __attribute__((ext_vector_type(4))) float f32x4;
typedef unsigned short u16;
typedef unsigned int u32;
typedef unsigned long long u64;

// Shapes: B=16, T_ENC=256, T_DEC=64, N_MEL=80, ENC=512, ARNN=DRNN=1024,
// PRENET=256, ATTN_DIM=128, LOC_F=32, LOC_K=31
// attn LSTM K = 1792 (56 tiles of 32); dec K = 2560 (80 tiles)
// MFMA 16x16x32 bf16; C/D: col=lane&15, row=(lane>>4)*4+reg  [HW-verified]
//
// r17 = r14 + hop-overhead cuts: (1) fast flags - wave 0 publishes gating
// data, waits ITS OWN vmcnt(0), stores flag (no block-wide drain barrier;
// t=63 keeps full drain for epilogue CTXF); (2) phase-B polls the 128 Af
// flags directly (16 pollers - no storm) skipping the aggregator hop.
// Coherence: writes agent-scope (LLC); reads plain cached on step-versioned
// virgin addresses (flag-gated; stale lines impossible; replay-safe).

// ---------------- workspace byte offsets ----------------
static constexpr size_t OFF_WFA   = 0;                 // 14,680,064
static constexpr size_t OFF_WFD   = 14680064;          // +20,971,520 = 35,651,584
static constexpr size_t OFF_PREF  = 35651584;          // +524,288
static constexpr size_t OFF_QWF   = 36175872;          // +262,144  qW A-frags (256 tiles)
static constexpr size_t OFF_MWT   = 36438016;          // +262,144
static constexpr size_t OFF_BA    = 36700160;          // +16,384
static constexpr size_t OFF_BD    = 36716544;          // +16,384
static constexpr size_t OFF_PM    = 36732928;          // +2,097,152  pm[b][tt][d] f32
static constexpr size_t OFF_CTXF  = 38830080;          // +2,129,920  [t][b][d] f32
static constexpr size_t OFF_DHF   = 40960000;          // +4,259,840  [t][u][b] f32
static constexpr size_t OFF_AHFD  = 45219840;          // +2,129,920  65 x 32KB frag
static constexpr size_t OFF_CTXFD = 47349760;          // +1,064,960  65 x 16KB frag
static constexpr size_t OFF_DHFD  = 48414720;          // +2,129,920  65 x 32KB frag
static constexpr size_t OFF_BAR   = 50544640;          // flags
static constexpr size_t OFF_END   = 50548736;
// flag layout within OFF_BAR: Af 128 packed u32 @0; Df 128 packed @1024;
// Bf 16 strided(x16) @2048; Aall @3072; Dall @3136; Ball @3200.

__device__ __forceinline__ float sigmf(float x) { return 1.f / (1.f + expf(-x)); }
__device__ __forceinline__ float tanh_fast(float x) {
  float e2 = __expf(2.f * x);
  return 1.f - 2.f / (e2 + 1.f);
}
__device__ __forceinline__ u16 f2bf(float f) {
  u32 u = __float_as_uint(f);
  return (u16)((u + 0x7FFFu + ((u >> 16) & 1u)) >> 16);
}
__device__ __forceinline__ float bf2f(u16 x) { return __uint_as_float(((u32)x) << 16); }

// cross-block fragment read: plain cached load (see coherence note above)
__device__ __forceinline__ short8 ld_frag(const void* p) {
  return *(const short8*)p;
}

// agent-scope helpers (UC path)
__device__ __forceinline__ void st_u16_agent(u16* p, u16 v) {
  __hip_atomic_store(p, v, __ATOMIC_RELAXED, __HIP_MEMORY_SCOPE_AGENT);
}
__device__ __forceinline__ void st_f32_agent(float* p, float v) {
  __hip_atomic_store(p, v, __ATOMIC_RELAXED, __HIP_MEMORY_SCOPE_AGENT);
}
__device__ __forceinline__ void st_u64_agent(u64* p, u64 v) {
  __hip_atomic_store(p, v, __ATOMIC_RELAXED, __HIP_MEMORY_SCOPE_AGENT);
}
__device__ __forceinline__ u32 ld_u32_agent(const u32* p) {
  return __hip_atomic_load(p, __ATOMIC_RELAXED, __HIP_MEMORY_SCOPE_AGENT);
}
__device__ __forceinline__ void st_u32_agent(u32* p, u32 v) {
  __hip_atomic_store(p, v, __ATOMIC_RELAXED, __HIP_MEMORY_SCOPE_AGENT);
}

// single-line, single-lane consumer wait (SLP compile-time const)
template <int SLP>
__device__ __forceinline__ void wait_one(const u32* f, u32 target, int th) {
  if (th == 0) {
    while (ld_u32_agent(f) < target) __builtin_amdgcn_s_sleep(SLP);
  }
  __syncthreads();
}
// 128 packed flags: first wave polls 2 lines per lane
template <int SLP>
__device__ __forceinline__ void wait_p128(const u32* F, u32 target, int th) {
  if (th < 64) {
    for (;;) {
      u32 v0 = ld_u32_agent(F + th);
      u32 v1 = ld_u32_agent(F + 64 + th);
      u32 mn = v0 < v1 ? v0 : v1;
      if (__all(mn >= target)) break;
      __builtin_amdgcn_s_sleep(SLP);
    }
  }
  __syncthreads();
}

// ---------------- prep: LSTM weights -> bf16 A-fragment layout ----------------
__global__ void k_wfrag(const float* __restrict__ Wih, const float* __restrict__ Whh,
                        char* __restrict__ dst, int NT, int Kih) {
  int idx = blockIdx.x * 256 + threadIdx.x;   // (tile*NT + s)*64 + l
  int l = idx & 63;
  int st = idx >> 6;
  int s = st % NT, tile = st / NT;
  int r = l & 15, kg = l >> 4;
  int j = (r >> 2) * 1024 + tile * 4 + (r & 3);
  int k0 = s * 32 + kg * 8;
  const float* src = (k0 < Kih) ? (Wih + (size_t)j * Kih + k0)
                                : (Whh + (size_t)j * 1024 + (k0 - Kih));
  short8 v;
#pragma unroll
  for (int e = 0; e < 8; ++e) v[e] = (short)f2bf(src[e]);
  *(short8*)(dst + (size_t)idx * 16) = v;
}

// ---------------- prep: qW -> bf16 A-fragments (8 d-tiles x 32 k-tiles) -------
__global__ void k_qwfrag(const float* __restrict__ qW, char* __restrict__ dst) {
  int idx = blockIdx.x * 256 + threadIdx.x;   // tile*64 + l, 16384 total
  int l = idx & 63, tile = idx >> 6;
  int dt = tile >> 5, kt = tile & 31;
  int j = dt * 16 + (l & 15);
  int k0 = kt * 32 + (l >> 4) * 8;
  short8 v;
#pragma unroll
  for (int e = 0; e < 8; ++e) v[e] = (short)f2bf(qW[j * 1024 + k0 + e]);
  *(short8*)(dst + (size_t)idx * 16) = v;
}

// ---------------- prep: memW^T, combined biases ----------------
__global__ void k_smallprep(const float* __restrict__ memW,
                            const float* __restrict__ abih, const float* __restrict__ abhh,
                            const float* __restrict__ dbih, const float* __restrict__ dbhh,
                            char* __restrict__ wsb) {
  int idx = blockIdx.x * 256 + threadIdx.x;
  if (idx < 65536) {
    int k = idx >> 7, d = idx & 127;
    ((float*)(wsb + OFF_MWT))[idx] = memW[d * 512 + k];
  } else if (idx < 69632) {
    int j = idx - 65536;
    ((float*)(wsb + OFF_BA))[j] = abih[j] + abhh[j];
  } else if (idx < 73728) {
    int j = idx - 69632;
    ((float*)(wsb + OFF_BD))[j] = dbih[j] + dbhh[j];
  }
}

// ---------------- prep: prenet -> bf16 B-fragment layout per step ----------------
__global__ void k_prenet(const float* __restrict__ dec_in,
                         const float* __restrict__ W1, const float* __restrict__ b1,
                         const float* __restrict__ W2, const float* __restrict__ b2,
                         char* __restrict__ wsb) {
  int s = blockIdx.x, b = blockIdx.y, th = threadIdx.x;
  __shared__ float frame[80];
  __shared__ float h1[256];
  if (th < 80) frame[th] = (s == 0) ? 0.f : dec_in[(b * 80 + th) * 64 + (s - 1)];
  __syncthreads();
  float a = b1[th];
  const float* w1r = W1 + th * 80;
  for (int m = 0; m < 80; ++m) a += w1r[m] * frame[m];
  h1[th] = fmaxf(a, 0.f);
  __syncthreads();
  float a2 = b2[th];
  const float* w2r = W2 + th * 256;
  for (int i = 0; i < 256; ++i) a2 += w2r[i] * h1[i];
  float pre = fmaxf(a2, 0.f);
  int k = th;
  ((u16*)(wsb + OFF_PREF))[(((size_t)s * 8 + (k >> 5)) * 64 + ((k >> 3) & 3) * 16 + b) * 8 + (k & 7)] = f2bf(pre);
}

// ---------------- prep: processed_memory pm[b][tt][d] ----------------
__global__ void k_pm(const float* __restrict__ memory, char* __restrict__ wsb) {
  int bk = blockIdx.x, th = threadIdx.x;
  int b = bk >> 4, t0 = (bk & 15) * 16;
  __shared__ float mrow[16 * 512];
  for (int i = 0; i < 8; ++i) {
    int fi4 = i * 256 + th;
    int tl = fi4 >> 7, k4 = (fi4 & 127) << 2;
    *(float4*)&mrow[tl * 512 + k4] =
        *(const float4*)&memory[((size_t)(b * 256 + t0 + tl)) * 512 + k4];
  }
  __syncthreads();
  int d = th & 127, tl0 = th >> 7;
  float acc[8] = {};
  const float* mWT = (const float*)(wsb + OFF_MWT);
  float* pmw = (float*)(wsb + OFF_PM);
  for (int k = 0; k < 512; ++k) {
    float w = mWT[k * 128 + d];
#pragma unroll
    for (int i = 0; i < 8; ++i) acc[i] += w * mrow[(tl0 + i * 2) * 512 + k];
  }
  for (int i = 0; i < 8; ++i)
    pmw[((size_t)(b * 256 + t0 + tl0 + i * 2)) * 128 + d] = acc[i];
}

struct KParams {
  const float* memory;
  const int* mlen;
  const float* convW;
  const float* ldW;
  const float* attnv;
  const float* projW;
  const float* projb;
  const float* gateW;
  const float* gateb;
  char* wsb;
  float* out;
};

// attn "early" tiles for step t: PREF (pe<8) + AHFD (pe>=8) -> 10 MFMA per wave
__device__ __forceinline__ f32x4 attn_early(char* wsb, int t, int kc, int l,
                                            const short8* afE) {
  f32x4 acc = {0.f, 0.f, 0.f, 0.f};
#pragma unroll
  for (int i = 0; i < 10; ++i) {
    int pe = kc * 10 + i;
    const char* src = (pe < 8)
        ? wsb + OFF_PREF + (((size_t)t * 8 + pe) * 64 + l) * 16
        : wsb + OFF_AHFD + (((size_t)t * 32 + (pe - 8)) * 64 + l) * 16;
    short8 bv = ld_frag(src);
    acc = __builtin_amdgcn_mfma_f32_16x16x32_bf16(afE[i], bv, acc, 0, 0, 0);
  }
  return acc;
}

// dec-LSTM step td = t-1 (reads AHFD[t], CTXFD[t], DHFD[t-1]; writes DHF[t], DHFD[t])
__device__ __forceinline__ void run_dec(char* wsb, int t, int tb, int th, int l, int w,
                                        int rt, int kc, float biasD_r, float& cD,
                                        float* smC) {
  const char* wfd = wsb + OFF_WFD;
  int tIdx = tb * 2 + rt;
  f32x4 acc = {0.f, 0.f, 0.f, 0.f};
#pragma unroll
  for (int i = 0; i < 20; ++i) {
    int kt = kc * 20 + i;
    short8 av = *(const short8*)(wfd + (((size_t)tIdx * 80 + kt) * 64 + l) * 16);
    const char* src;
    if (kt < 32)      src = wsb + OFF_AHFD + (((size_t)t * 32 + kt) * 64 + l) * 16;
    else if (kt < 48) src = wsb + OFF_CTXFD + (((size_t)t * 16 + (kt - 32)) * 64 + l) * 16;
    else              src = wsb + OFF_DHFD + (((size_t)(t - 1) * 32 + (kt - 48)) * 64 + l) * 16;
    short8 bv = ld_frag(src);
    acc = __builtin_amdgcn_mfma_f32_16x16x32_bf16(av, bv, acc, 0, 0, 0);
  }
#pragma unroll
  for (int r4 = 0; r4 < 4; ++r4)
    smC[w * 256 + ((l >> 4) * 4 + r4) * 16 + (l & 15)] = acc[r4];
  __syncthreads();
  {
    int rt2 = th >> 8, r = (th >> 4) & 15, b2 = th & 15;
    float s = 0.f;
#pragma unroll
    for (int q = 0; q < 4; ++q) s += smC[(q * 2 + rt2) * 256 + r * 16 + b2];
    smC[4096 + th] = s + biasD_r;
  }
  __syncthreads();
  if (th < 128) {
    int b = th & 15, lu = th >> 4;
    int rt3 = lu >> 2, ul = lu & 3;
    int u = (tb * 2 + rt3) * 4 + ul;
    float gi = smC[4096 + rt3 * 256 + ul * 16 + b];
    float gf = smC[4096 + rt3 * 256 + (4 + ul) * 16 + b];
    float gc = smC[4096 + rt3 * 256 + (8 + ul) * 16 + b];
    float go = smC[4096 + rt3 * 256 + (12 + ul) * 16 + b];
    float c2 = sigmf(gf) * cD + sigmf(gi) * tanhf(gc);
    float h2 = sigmf(go) * tanhf(c2);
    cD = c2;
    st_f32_agent((float*)(wsb + OFF_DHF) + ((size_t)t * 1024 + u) * 16 + b, h2);
    st_u16_agent((u16*)(wsb + OFF_DHFD) +
                 ((((size_t)t * 32 + (u >> 5)) * 64 + ((u >> 3) & 3) * 16 + b) * 8 + (u & 7)),
                 f2bf(h2));
  }
}

// ---------------- main persistent kernel (dataflow + flag aggregation) ---------
// Roles: bk 0..15: conv(t) + phase-B(t), publish Bf (fast flag).
//        bk 16..143: late-attn(t) on Ball; early-attn(t+1) + dec(t-1) in shadow.
//        bk 144/145/146: aggregators Af->Aall, Df->Dall, Bf->Ball.
//        bk 147..255: idle; epilogue (all blocks).
__global__ void __launch_bounds__(512, 1) k_main(KParams p) {
  const int th = threadIdx.x;
  const int bk = blockIdx.x;
  char* wsb = p.wsb;
  const int l = th & 63, w = th >> 6;
  u32* Af = (u32*)(wsb + OFF_BAR);            // 128 packed
  u32* Df = (u32*)(wsb + OFF_BAR + 1024);     // 128 packed
  u32* Bf = (u32*)(wsb + OFF_BAR + 2048);     // 16 strided (x16 u32)
  u32* Aall = (u32*)(wsb + OFF_BAR + 3072);
  u32* Dall = (u32*)(wsb + OFF_BAR + 3136);
  u32* Ball = (u32*)(wsb + OFF_BAR + 3200);

  __shared__ float smC[4608];
  __shared__ float s2q[128], s2v[128];
  __shared__ u16 s_convF[8192];               // conv bf16 A-frags: [16 tiles][64][8]
  __shared__ u16 s_pack[512];                 // publish pack buffer
  __shared__ float s_e[256], s3wr[4];
  __shared__ float s1cw[1984];                // convW 32*62
  __shared__ float s_aw[256], s_awc[256];     // per-b attention state (blocks 0..15)

  const float* pm = (const float*)(wsb + OFF_PM);

  if (bk < 16) {
    for (int i = th; i < 1984; i += 512) s1cw[i] = p.convW[i];
    for (int i = th; i < 4096; i += 512) ((u32*)s_convF)[i] = 0u;
    if (th < 128) s2v[th] = p.attnv[th];
    if (th < 256) { s_aw[th] = 0.f; s_awc[th] = 0.f; }
  }

  float biasA_r = 0.f, biasD_r = 0.f;
  if (bk >= 16 && bk < 144) {
    int r = (th >> 4) & 15, rt2 = th >> 8, tbase = (bk - 16) * 2;
    biasA_r = ((const float*)(wsb + OFF_BA))[(r >> 2) * 1024 + (tbase + rt2) * 4 + (r & 3)];
    biasD_r = ((const float*)(wsb + OFF_BD))[(r >> 2) * 1024 + (tbase + rt2) * 4 + (r & 3)];
  }
  int lenB = 0;
  if (bk < 16) lenB = p.mlen[bk];
  float cA = 0.f, cD = 0.f;

  const int rt = w & 1, kc = w >> 1;
  short8 afE[10], afL[4];
  if (bk >= 16 && bk < 144) {
    const char* wfa = wsb + OFF_WFA;
    int tIdx = (bk - 16) * 2 + rt;
#pragma unroll
    for (int i = 0; i < 10; ++i) {
      int pe = kc * 10 + i;
      int kt = (pe < 8) ? pe : (24 + (pe - 8));
      afE[i] = *(const short8*)(wfa + (((size_t)tIdx * 56 + kt) * 64 + l) * 16);
    }
#pragma unroll
    for (int i = 0; i < 4; ++i) {
      int kt = 8 + kc * 4 + i;
      afL[i] = *(const short8*)(wfa + (((size_t)tIdx * 56 + kt) * 64 + l) * 16);
    }
  }
  // ldw B-frags in registers (phase-B blocks)
  short8 ldwB[8];
  if (bk < 16) {
    int kg = l >> 4, dcol = l & 15;
#pragma unroll
    for (int dt = 0; dt < 8; ++dt) {
      short8 v;
#pragma unroll
      for (int e = 0; e < 8; ++e)
        v[e] = (short)f2bf(p.ldW[(dt * 16 + dcol) * 32 + kg * 8 + e]);
      ldwB[dt] = v;
    }
  }
  __syncthreads();

  if (bk >= 16 && bk < 144) {
    // ============== attn (early/late) + dec pipeline ==============
    const int tb = bk - 16;
    f32x4 acc = attn_early(wsb, 0, kc, l, afE);   // slot-0 inputs (zeroed/ready)
    for (int t = 0; t < 64; ++t) {
      wait_one<1>(Ball, (u32)t, th);              // ctx(t-1) published
#pragma unroll
      for (int i = 0; i < 4; ++i) {
        int ct = kc * 4 + i;
        short8 bv = ld_frag(wsb + OFF_CTXFD + (((size_t)t * 16 + ct) * 64 + l) * 16);
        acc = __builtin_amdgcn_mfma_f32_16x16x32_bf16(afL[i], bv, acc, 0, 0, 0);
      }
#pragma unroll
      for (int r4 = 0; r4 < 4; ++r4)
        smC[w * 256 + ((l >> 4) * 4 + r4) * 16 + (l & 15)] = acc[r4];
      __syncthreads();
      {
        int rt2 = th >> 8, r = (th >> 4) & 15, b2 = th & 15;
        float s = 0.f;
#pragma unroll
        for (int q = 0; q < 4; ++q) s += smC[(q * 2 + rt2) * 256 + r * 16 + b2];
        smC[4096 + th] = s + biasA_r;
      }
      __syncthreads();
      if (th < 128) {
        int b = th & 15, lu = th >> 4;
        float gi = smC[4096 + (lu >> 2) * 256 + (lu & 3) * 16 + b];
        float gf = smC[4096 + (lu >> 2) * 256 + (4 + (lu & 3)) * 16 + b];
        float gc = smC[4096 + (lu >> 2) * 256 + (8 + (lu & 3)) * 16 + b];
        float go = smC[4096 + (lu >> 2) * 256 + (12 + (lu & 3)) * 16 + b];
        float c2 = sigmf(gf) * cA + sigmf(gi) * tanhf(gc);
        float h2 = sigmf(go) * tanhf(c2);
        cA = c2;
        s_pack[b * 8 + lu] = f2bf(h2);            // u = tb*8 + lu
      }
      __syncthreads();
      if (th < 16) {  // coalesced AHFD publish: 16 b x 16B contiguous (256B)
        const u64* src = (const u64*)s_pack + th * 2;
        u64* dst = (u64*)(wsb + OFF_AHFD + ((size_t)(t + 1) * 32 + (tb >> 2)) * 1024 +
                          ((size_t)(tb & 3) * 16 + th) * 16);
        st_u64_agent(dst, src[0]);
        st_u64_agent(dst + 1, src[1]);
      }
      // fast flag: wave 0 drains ITS OWN stores, lane 0 publishes Af
      if (w == 0) {
        asm volatile("s_waitcnt vmcnt(0)" ::: "memory");
        if (l == 0) st_u32_agent(Af + tb, (u32)(t + 1));
      }
      if (t >= 1) {
        wait_one<1>(Dall, (u32)(t - 1), th);
        run_dec(wsb, t, tb, th, l, w, rt, kc, biasD_r, cD, smC);
        __syncthreads();
        if (th == 0) st_u32_agent(Df + tb, (u32)t);
      }
      if (t < 63) {
        wait_one<1>(Aall, (u32)(t + 1), th);      // ah(t) fully published
        acc = attn_early(wsb, t + 1, kc, l, afE);
      }
    }
    // tail: dec(63)
    wait_one<1>(Ball, 64u, th);
    wait_one<1>(Dall, 63u, th);
    run_dec(wsb, 64, tb, th, l, w, rt, kc, biasD_r, cD, smC);
    __syncthreads();
    if (th == 0) st_u32_agent(Df + tb, 64u);
  } else if (bk < 16) {
    // ============== conv + phase-B pipeline ==============
    const int b = bk;
    for (int t = 0; t < 64; ++t) {
      {  // conv(t) from own-LDS aw/awc -> bf16 A-frag layout in s_convF
        int jmax = (lenB + 15) >> 4;
        for (int jj = 0; jj < jmax; ++jj) {
          int idx = jj * 512 + th, tt = idx >> 5, f = idx & 31;
          float a = 0.f;
          const float* w0 = s1cw + f * 62;
#pragma unroll
          for (int kk = 0; kk < 31; ++kk) {
            int pos = tt + kk - 15;
            bool ok = (pos >= 0 && pos < 256);
            float awv = ok ? s_aw[pos] : 0.f;
            float awcv = ok ? s_awc[pos] : 0.f;
            a += awv * w0[kk] + awcv * w0[31 + kk];
          }
          s_convF[(tt >> 4) * 512 + ((f >> 3) * 16 + (tt & 15)) * 8 + (f & 7)] = f2bf(a);
        }
      }
      wait_p128<1>(Af, (u32)(t + 1), th);       // ah(t) published (direct, no hop)
      {  // query via MFMA: wave w = d-tile; ah octets as broadcast B-frags
        f32x4 qacc = {0.f, 0.f, 0.f, 0.f};
        const char* qwf = wsb + OFF_QWF;
#pragma unroll 4
        for (int kt = 0; kt < 32; ++kt) {
          short8 av = *(const short8*)(qwf + (((size_t)w * 32 + kt) * 64 + l) * 16);
          short8 bv = ld_frag(wsb + OFF_AHFD + ((size_t)(t + 1) * 32 + kt) * 1024 +
                              ((size_t)(l >> 4) * 16 + b) * 16);
          qacc = __builtin_amdgcn_mfma_f32_16x16x32_bf16(av, bv, qacc, 0, 0, 0);
        }
        if ((l & 15) == 0) {
          int r0 = (l >> 4) * 4;
          s2q[w * 16 + r0]     = qacc[0];
          s2q[w * 16 + r0 + 1] = qacc[1];
          s2q[w * 16 + r0 + 2] = qacc[2];
          s2q[w * 16 + r0 + 3] = qacc[3];
        }
      }
      __syncthreads();
      {  // energies via MFMA: wave w owns tt-tiles {2w, 2w+1}
#pragma unroll
        for (int tl = 0; tl < 2; ++tl) {
          int ttile = w * 2 + tl;
          short8 afc = *(const short8*)&s_convF[ttile * 512 + l * 8];
          int dcol = l & 15;
          float e0 = 0.f, e1 = 0.f, e2 = 0.f, e3 = 0.f;
          const float* pmb = pm + ((size_t)(b * 256 + ttile * 16 + (l >> 4) * 4)) * 128 + dcol;
#pragma unroll
          for (int dt = 0; dt < 8; ++dt) {
            f32x4 S = {0.f, 0.f, 0.f, 0.f};
            S = __builtin_amdgcn_mfma_f32_16x16x32_bf16(afc, ldwB[dt], S, 0, 0, 0);
            int d = dt * 16 + dcol;
            float qd = s2q[d], vd = s2v[d];
            e0 += vd * tanh_fast(qd + pmb[dt * 16 + 0 * 128] + S[0]);
            e1 += vd * tanh_fast(qd + pmb[dt * 16 + 1 * 128] + S[1]);
            e2 += vd * tanh_fast(qd + pmb[dt * 16 + 2 * 128] + S[2]);
            e3 += vd * tanh_fast(qd + pmb[dt * 16 + 3 * 128] + S[3]);
          }
#pragma unroll
          for (int off = 8; off; off >>= 1) {
            e0 += __shfl_xor(e0, off);
            e1 += __shfl_xor(e1, off);
            e2 += __shfl_xor(e2, off);
            e3 += __shfl_xor(e3, off);
          }
          if ((l & 15) == 0) {
            int tb0 = ttile * 16 + (l >> 4) * 4;
            s_e[tb0]     = (tb0     < lenB) ? __expf(e0) : 0.f;
            s_e[tb0 + 1] = (tb0 + 1 < lenB) ? __expf(e1) : 0.f;
            s_e[tb0 + 2] = (tb0 + 2 < lenB) ? __expf(e2) : 0.f;
            s_e[tb0 + 3] = (tb0 + 3 < lenB) ? __expf(e3) : 0.f;
          }
        }
      }
      __syncthreads();
      if (th < 256) {
        float v0 = s_e[th];
#pragma unroll
        for (int off = 32; off; off >>= 1) v0 += __shfl_xor(v0, off);
        if ((th & 63) == 0) s3wr[th >> 6] = v0;
      }
      __syncthreads();
      float rden = 1.f / (s3wr[0] + s3wr[1] + s3wr[2] + s3wr[3]);
      if (th < 256) {
        float a = s_e[th] * rden;
        s_aw[th] = a;
        s_awc[th] += a;
        p.out[82944 + ((size_t)(b * 64 + t)) * 256 + th] = a;
      }
      __syncthreads();
      {  // context: plain loads of memory (read-only, L2-resident)
        int dq = th & 127, tg = th >> 7;
        int d0 = dq * 4;
        float a0 = 0.f, a1 = 0.f, a2 = 0.f, a3 = 0.f;
        const float* mb = p.memory + ((size_t)b * 256) * 512 + d0;
        for (int tt = tg; tt < lenB; tt += 4) {
          float4 mv = *(const float4*)(mb + (size_t)tt * 512);
          float aw = s_aw[tt];
          a0 += aw * mv.x; a1 += aw * mv.y; a2 += aw * mv.z; a3 += aw * mv.w;
        }
        smC[tg * 512 + d0]     = a0;
        smC[tg * 512 + d0 + 1] = a1;
        smC[tg * 512 + d0 + 2] = a2;
        smC[tg * 512 + d0 + 3] = a3;
      }
      __syncthreads();
      {
        int d = th;
        float ctxv = smC[d] + smC[512 + d] + smC[1024 + d] + smC[1536 + d];
        st_f32_agent((float*)(wsb + OFF_CTXF) + (size_t)(t + 1) * 8192 + b * 512 + d, ctxv);
        s_pack[d] = f2bf(ctxv);
      }
      __syncthreads();
      if (th < 64) {  // coalesced CTXFD publish: octet o = th (wave 0)
        u64 p0 = ((const u64*)s_pack)[th * 2];
        u64 p1 = ((const u64*)s_pack)[th * 2 + 1];
        u64* dst = (u64*)(wsb + OFF_CTXFD + ((size_t)(t + 1) * 16 + (th >> 2)) * 1024 +
                          ((size_t)(th & 3) * 16 + b) * 16);
        st_u64_agent(dst, p0);
        st_u64_agent(dst + 1, p1);
      }
      if (t == 63) {
        __syncthreads();                        // full drain (epilogue reads CTXF)
        if (th == 0) st_u32_agent(Bf + b * 16, 64u);
      } else if (w == 0) {
        asm volatile("s_waitcnt vmcnt(0)" ::: "memory");
        if (l == 0) st_u32_agent(Bf + b * 16, (u32)(t + 1));
      }
    }
  } else if (bk == 144) {
    // aggregator: Af (128 packed) -> Aall
    if (th < 64) {
      for (u32 tgt = 1; tgt <= 64; ++tgt) {
        for (;;) {
          u32 v0 = ld_u32_agent(Af + th);
          u32 v1 = ld_u32_agent(Af + 64 + th);
          u32 mn = v0 < v1 ? v0 : v1;
          if (__all(mn >= tgt)) break;
          __builtin_amdgcn_s_sleep(1);
        }
        if (th == 0) st_u32_agent(Aall, tgt);
      }
    }
    __syncthreads();
  } else if (bk == 145) {
    // aggregator: Df (128 packed) -> Dall
    if (th < 64) {
      for (u32 tgt = 1; tgt <= 64; ++tgt) {
        for (;;) {
          u32 v0 = ld_u32_agent(Df + th);
          u32 v1 = ld_u32_agent(Df + 64 + th);
          u32 mn = v0 < v1 ? v0 : v1;
          if (__all(mn >= tgt)) break;
          __builtin_amdgcn_s_sleep(1);
        }
        if (th == 0) st_u32_agent(Dall, tgt);
      }
    }
    __syncthreads();
  } else if (bk == 146) {
    // aggregator: Bf (16 strided) -> Ball
    if (th < 64) {
      for (u32 tgt = 1; tgt <= 64; ++tgt) {
        for (;;) {
          u32 v = ld_u32_agent(Bf + (th & 15) * 16);
          if (__all(v >= tgt)) break;
          __builtin_amdgcn_s_sleep(1);
        }
        if (th == 0) st_u32_agent(Ball, tgt);
      }
    }
    __syncthreads();
  }

  // ================= final dataflow sync + epilogue =================
  if (bk >= 147) {
    wait_one<64>(Dall, 64u, th);
    wait_one<64>(Ball, 64u, th);
  } else {
    wait_one<4>(Dall, 64u, th);
    wait_one<4>(Ball, 64u, th);
  }
  {
    int t = bk & 63, pa = bk >> 6;
    const float* dh = (const float*)(wsb + OFF_DHF) + (size_t)(t + 1) * 16384;
    const float* cxt = (const float*)(wsb + OFF_CTXF) + (size_t)(t + 1) * 8192;
    int lim = (pa == 3) ? 336 : 320;
    for (int idx = th; idx < lim; idx += 512) {
      if (idx < 320) {
        int mi = idx >> 4, b = idx & 15, m = pa * 20 + mi;
        const float* wr = p.projW + (size_t)m * 1536;
        const float* cxb = cxt + b * 512;
        float a0 = 0.f, a1 = 0.f;
#pragma unroll 8
        for (int k = 0; k < 1024; k += 2) { a0 += wr[k] * dh[k * 16 + b]; a1 += wr[k + 1] * dh[(k + 1) * 16 + b]; }
#pragma unroll 8
        for (int k = 0; k < 512; k += 2)  { a0 += wr[1024 + k] * cxb[k]; a1 += wr[1025 + k] * cxb[k + 1]; }
        p.out[((size_t)(b * 80 + m)) * 64 + t] = a0 + a1 + p.projb[m];
      } else {
        int b = idx - 320;
        const float* cxb = cxt + b * 512;
        float a0 = 0.f, a1 = 0.f;
#pragma unroll 8
        for (int k = 0; k < 1024; k += 2) { a0 += p.gateW[k] * dh[k * 16 + b]; a1 += p.gateW[k + 1] * dh[(k + 1) * 16 + b]; }
#pragma unroll 8
        for (int k = 0; k < 512; k += 2)  { a0 += p.gateW[1024 + k] * cxb[k]; a1 += p.gateW[1025 + k] * cxb[k + 1]; }
        p.out[81920 + b * 64 + t] = a0 + a1 + p.gateb[0];
      }
    }
  }
}

// ---------------- host launcher ----------------
extern "C" void kernel_launch(void* const* d_in, const int* in_sizes, int n_in,
                              void* d_out, int out_size, void* d_ws, size_t ws_size,
                              hipStream_t stream) {
  (void)in_sizes; (void)n_in; (void)out_size; (void)ws_size;
  const float* memory = (const float*)d_in[0];
  const float* dec_in = (const float*)d_in[1];
  const int*   mlen   = (const int*)d_in[2];
  const float* pW1    = (const float*)d_in[3];
  const float* pb1    = (const float*)d_in[4];
  const float* pW2    = (const float*)d_in[5];
  const float* pb2    = (const float*)d_in[6];
  const float* aWih   = (const float*)d_in[7];
  const float* aWhh   = (const float*)d_in[8];
  const float* abih   = (const float*)d_in[9];
  const float* abhh   = (const float*)d_in[10];
  const float* qW     = (const float*)d_in[11];
  const float* memW   = (const float*)d_in[12];
  const float* convW  = (const float*)d_in[13];
  const float* ldW    = (const float*)d_in[14];
  const float* attnv  = (const float*)d_in[15];
  const float* dWih   = (const float*)d_in[16];
  const float* dWhh   = (const float*)d_in[17];
  const float* dbih   = (const float*)d_in[18];
  const float* dbhh   = (const float*)d_in[19];
  const float* projW  = (const float*)d_in[20];
  const float* projb  = (const float*)d_in[21];
  const float* gateW  = (const float*)d_in[22];
  const float* gateb  = (const float*)d_in[23];
  char* wsb = (char*)d_ws;
  float* out = (float*)d_out;

  // zero slot-0 fragments (initial states) + flag words (replay-safe)
  hipMemsetAsync(wsb + OFF_AHFD, 0, 32768, stream);
  hipMemsetAsync(wsb + OFF_CTXFD, 0, 16384, stream);
  hipMemsetAsync(wsb + OFF_DHFD, 0, 32768, stream);
  hipMemsetAsync(wsb + OFF_BAR, 0, 4096, stream);

  hipLaunchKernelGGL(k_wfrag, dim3(3584), dim3(256), 0, stream, aWih, aWhh, wsb + OFF_WFA, 56, 768);
  hipLaunchKernelGGL(k_wfrag, dim3(5120), dim3(256), 0, stream, dWih, dWhh, wsb + OFF_WFD, 80, 1536);
  hipLaunchKernelGGL(k_qwfrag, dim3(64), dim3(256), 0, stream, qW, wsb + OFF_QWF);
  hipLaunchKernelGGL(k_smallprep, dim3(288), dim3(256), 0, stream, memW, abih, abhh, dbih, dbhh, wsb);
  hipLaunchKernelGGL(k_prenet, dim3(64, 16), dim3(256), 0, stream, dec_in, pW1, pb1, pW2, pb2, wsb);
  hipLaunchKernelGGL(k_pm, dim3(256), dim3(256), 0, stream, memory, wsb);

  KParams p{memory, mlen, convW, ldW, attnv, projW, projb, gateW, gateb, wsb, out};
  void* args[] = { &p };
  hipLaunchCooperativeKernel((void*)k_main, dim3(256), dim3(512), args, 0, stream);
}